// Round 1
// baseline (870.756 us; speedup 1.0000x reference)
//
#include <hip/hip_runtime.h>

using bf16_t = __bf16;
using bf16x4 = __bf16 __attribute__((ext_vector_type(4)));
using bf16x8 = __bf16 __attribute__((ext_vector_type(8)));
using f32x4  = float  __attribute__((ext_vector_type(4)));

#define MFMA16(a, b, c) __builtin_amdgcn_mfma_f32_16x16x32_bf16((a), (b), (c), 0, 0, 0)

// 8-byte-aligned bf16x8 load as two b64s
__device__ __forceinline__ bf16x8 ld_b8_2x(const bf16_t* p) {
    bf16x4 lo = *(const bf16x4*)p;
    bf16x4 hi = *(const bf16x4*)(p + 4);
    bf16x8 r;
    r[0] = lo[0]; r[1] = lo[1]; r[2] = lo[2]; r[3] = lo[3];
    r[4] = hi[0]; r[5] = hi[1]; r[6] = hi[2]; r[7] = hi[3];
    return r;
}

// ---------------------------------------------------------------------------
// Prep: swizzle weights into fragment order (bf16) in workspace. (unchanged)
//  wA  [mt(36)][ks(6)][lane(64)][8] : A-frag of w_qkv^T
//  w2B [ks(6)][nt(12)][lane(64)][8] : B-frag of w_proj
// ---------------------------------------------------------------------------
__global__ void prep_weights(const float* __restrict__ wqkv,
                             const float* __restrict__ wproj,
                             bf16_t* __restrict__ wA,
                             bf16_t* __restrict__ w2B) {
    int idx = blockIdx.x * 256 + threadIdx.x;
    const int N1 = 36 * 6 * 64 * 8;  // 110592
    if (idx < N1) {
        int j = idx & 7, L = (idx >> 3) & 63, q = idx >> 9;
        int ks = q % 6, mt = q / 6;
        int cc = ks * 32 + (L >> 4) * 8 + j;
        int ch = mt * 16 + (L & 15);
        wA[idx] = (bf16_t)wqkv[cc * 576 + ch];
    } else {
        int idx2 = idx - N1;
        if (idx2 < 6 * 12 * 64 * 8) {
            int j = idx2 & 7, L = (idx2 >> 3) & 63, q = idx2 >> 9;
            int nt = q % 12, ks = q / 12;
            int cc = ks * 32 + (L >> 4) * 8 + j;
            int ch = nt * 16 + (L & 15);
            w2B[idx2] = (bf16_t)wproj[cc * 192 + ch];
        }
    }
}

// ---------------------------------------------------------------------------
// Persistent fused window attention: 256 blocks x 1024 threads, 16 windows/blk
// (window w = blockIdx.x + 256*it; note 256 % 64 == 0 -> mask is per-block
//  constant and staged once).
//
// LDS map (bytes), total 145920:
//   [0,      30720)  qS  [6][64][40]     (aliased after PV by aoS [64][204])
//   [30720,  61440)  kS  [6][64][40]
//   [61440,  87552)  vT  [6][32][68]     V TRANSPOSED: [head][d][tok]
//   [87552,  96768)  pmS [64][72]        (static, staged once)
//   [96768, 145920)  region R: xS [64][204] (phase A input, prefetched)
//                    aliased by pS [6][64][128B] XOR-chunk-swizzled (phase B)
// Barriers/window: B1 (qkv ready), B2e (q/k frag reads done; cheap),
//   B3 (PV+ao done; R free), B4 (Ao hoisted + next-x written).
// ---------------------------------------------------------------------------
__global__ __launch_bounds__(1024, 4) void fused_window_attn(
    const float* __restrict__ x,     // [4096][49][192]
    const float* __restrict__ mask,  // [64][1][49][49]
    const bf16_t* __restrict__ wA,
    const bf16_t* __restrict__ w2B,
    const float* __restrict__ bias,  // [192]
    float* __restrict__ out)         // [4096][49][192]
{
    constexpr int QP  = 40;   // q/k pitch (elems)
    constexpr int VTP = 68;   // vT pitch (elems) [d-major]
    constexpr int PMP = 72;   // premask pitch
    constexpr int AOP = 204;  // attn_out / staged-x pitch

    __shared__ __align__(16) char smem[145920];
    bf16_t* qS  = (bf16_t*)smem;            // elem offsets
    bf16_t* kS  = qS + 15360;
    bf16_t* vT  = qS + 30720;               // [6][32][68]
    bf16_t* pmS = qS + 43776;
    char*   pB  = smem + 96768;             // swizzled P (byte-addressed)
    bf16_t* xS  = (bf16_t*)(smem + 96768);  // [64][204] (alias pB)
    bf16_t* aoS = (bf16_t*)smem;            // alias qS

    const int b    = blockIdx.x;   // 0..255
    const int tid  = threadIdx.x;
    const int wid  = tid >> 6;     // 0..15
    const int lane = tid & 63;
    const int g    = lane >> 4;
    const int c    = lane & 15;

    // ---- per-thread x staging chunk map (64*48 f32x4 chunks / 1024 thr) ----
    int tokA[3], cA[3];
#pragma unroll
    for (int i2 = 0; i2 < 3; ++i2) {
        int ch4 = tid + 1024 * i2;
        tokA[i2] = ch4 / 48;
        cA[i2]   = ch4 % 48;
    }

    // ---- stage premask ONCE (same mask for all 16 windows of this block) ----
    const float* mw = mask + (size_t)(b & 63) * 2401;
    for (int idx = tid; idx < 64 * 64; idx += 1024) {
        int i = idx >> 6, t = idx & 63;
        float v;
        if (t < 49) v = (i < 49) ? mw[i * 49 + t] : 0.0f;
        else        v = -1e30f;
        pmS[i * PMP + t] = (bf16_t)v;
    }

    // ---- load + write x for window 0 ----
    f32x4 xr[3];
    {
        const float* xb = x + (size_t)b * 9408;
#pragma unroll
        for (int i2 = 0; i2 < 3; ++i2)
            xr[i2] = (tokA[i2] < 49) ? *(const f32x4*)(xb + tokA[i2] * 192 + cA[i2] * 4)
                                     : (f32x4){0.f, 0.f, 0.f, 0.f};
    }
#pragma unroll
    for (int i2 = 0; i2 < 3; ++i2) {
        f32x4 v = xr[i2];
        bf16x4 o = {(bf16_t)v[0], (bf16_t)v[1], (bf16_t)v[2], (bf16_t)v[3]};
        *(bf16x4*)(xS + tokA[i2] * AOP + cA[i2] * 4) = o;
    }
    __syncthreads();  // pmS + xS(window 0) ready

    // wave task assignments (constant across windows)
    const int nmt = (wid < 4) ? 3 : 2;
    const int mt0 = (wid < 4) ? wid * 3 : 12 + (wid - 4) * 2;
    const int h   = wid >> 1;   // phase B: head
    const int u   = wid & 1;    // phase B: i-half
    const int mtc = wid & 3;    // phase C: token mtile
    const int g3  = wid >> 2;   // phase C: ntile group

    // hoist bias (fixed channels per thread)
    float bbv[3];
#pragma unroll
    for (int j = 0; j < 3; ++j) bbv[j] = bias[(g3 * 3 + j) * 16 + c];

#pragma unroll 1
    for (int it = 0; it < 16; ++it) {
        // =========== Phase A: qkv^T = w_qkv^T (A) * x^T (B) ===========
        f32x4 acc[3][4];
#pragma unroll
        for (int m = 0; m < 3; ++m)
#pragma unroll
            for (int n = 0; n < 4; ++n) acc[m][n] = (f32x4){0.f, 0.f, 0.f, 0.f};

        bf16x8 Afc[3];
#pragma unroll
        for (int m = 0; m < 3; ++m)
            if (m < nmt)
                Afc[m] = *(const bf16x8*)(wA + (((size_t)(mt0 + m) * 6 + 0) * 64 + lane) * 8);

#pragma unroll
        for (int ks = 0; ks < 6; ++ks) {
            bf16x8 Bf[4];
#pragma unroll
            for (int nt = 0; nt < 4; ++nt)
                Bf[nt] = ld_b8_2x(xS + (nt * 16 + c) * AOP + ks * 32 + g * 8);
            bf16x8 Afn[3];
            if (ks < 5) {
#pragma unroll
                for (int m = 0; m < 3; ++m)
                    if (m < nmt)
                        Afn[m] = *(const bf16x8*)(wA + (((size_t)(mt0 + m) * 6 + ks + 1) * 64 + lane) * 8);
            }
#pragma unroll
            for (int m = 0; m < 3; ++m) {
                if (m < nmt) {
#pragma unroll
                    for (int nt = 0; nt < 4; ++nt)
                        acc[m][nt] = MFMA16(Afc[m], Bf[nt], acc[m][nt]);
                }
            }
            if (ks < 5) {
#pragma unroll
                for (int m = 0; m < 3; ++m) Afc[m] = Afn[m];
            }
        }

        // prefetch next window's x into regs — issued AFTER phase A's global
        // loads (vmcnt is FIFO: issuing these first would make phase A's
        // s_waitcnt for wA also wait on these HBM loads)
        if (it < 15) {
            const float* xb = x + (size_t)(b + 256 * (it + 1)) * 9408;
#pragma unroll
            for (int i2 = 0; i2 < 3; ++i2)
                xr[i2] = (tokA[i2] < 49) ? *(const f32x4*)(xb + tokA[i2] * 192 + cA[i2] * 4)
                                         : (f32x4){0.f, 0.f, 0.f, 0.f};
        }

        // route: q,k -> [h][tok][40] row-major; v -> TRANSPOSED [h][d][68]
#pragma unroll
        for (int m = 0; m < 3; ++m) {
            if (m < nmt) {
                int mt  = mt0 + m;
                int typ = mt / 12;                       // wave-uniform
                int rel = (mt - typ * 12) * 16 + g * 4;  // 0..191 in q/k/v
                int hh  = rel >> 5;
                int dd0 = rel & 31;
#pragma unroll
                for (int nt = 0; nt < 4; ++nt) {
                    int tok = nt * 16 + c;
                    f32x4 a = acc[m][nt];
                    if (typ == 2) {
#pragma unroll
                        for (int r = 0; r < 4; ++r)
                            vT[hh * 2176 + (dd0 + r) * VTP + tok] = (bf16_t)a[r];
                    } else {
                        bf16x4 v4 = {(bf16_t)a[0], (bf16_t)a[1], (bf16_t)a[2], (bf16_t)a[3]};
                        if (typ == 0) *(bf16x4*)(qS + hh * 2560 + tok * QP + dd0) = v4;
                        else          *(bf16x4*)(kS + hh * 2560 + tok * QP + dd0) = v4;
                    }
                }
            }
        }
        __syncthreads();  // B1: qkv ready; xS dead (becomes pS)

        // =========== Phase B: attention. 12 wave-tasks = head(6) x half(2) ==
        bf16x8 Ak[4], Bq[2];
        if (wid < 12) {
            const bf16_t* qh = qS + h * 2560;
            const bf16_t* kh = kS + h * 2560;
#pragma unroll
            for (int mt = 0; mt < 4; ++mt)
                Ak[mt] = *(const bf16x8*)(kh + (mt * 16 + c) * QP + g * 8);
#pragma unroll
            for (int nl = 0; nl < 2; ++nl)
                Bq[nl] = *(const bf16x8*)(qh + ((2 * u + nl) * 16 + c) * QP + g * 8);
        }
        __syncthreads();  // B2e (cheap): all qS/kS reads complete -> ao writes OK

        f32x4 oacc[2][2];
#pragma unroll
        for (int a0 = 0; a0 < 2; ++a0)
#pragma unroll
            for (int a1 = 0; a1 < 2; ++a1) oacc[a0][a1] = (f32x4){0.f, 0.f, 0.f, 0.f};

        if (wid < 12) {
            char*         Ph = pB + h * 8192;   // 64 rows x 128 B, swizzled
            const bf16_t* vh = vT + h * 2176;

            // S^T[t][i] = sum_d k[t][d] q[i][d]
            f32x4 sacc[4][2];
#pragma unroll
            for (int mt = 0; mt < 4; ++mt)
#pragma unroll
                for (int nl = 0; nl < 2; ++nl) sacc[mt][nl] = (f32x4){0.f, 0.f, 0.f, 0.f};
#pragma unroll
            for (int mt = 0; mt < 4; ++mt)
#pragma unroll
                for (int nl = 0; nl < 2; ++nl)
                    sacc[mt][nl] = MFMA16(Ak[mt], Bq[nl], sacc[mt][nl]);

            const float scale = 0.17677669529663687f;  // 32^-0.5
#pragma unroll
            for (int nl = 0; nl < 2; ++nl) {
                int i = (2 * u + nl) * 16 + c;
                float s[16];
#pragma unroll
                for (int mt = 0; mt < 4; ++mt) {
                    bf16x4 pmv = *(const bf16x4*)(pmS + i * PMP + mt * 16 + g * 4);
#pragma unroll
                    for (int r = 0; r < 4; ++r)
                        s[mt * 4 + r] = sacc[mt][nl][r] * scale + (float)pmv[r];
                }
                // tree max (depth 4, max3-fusable)
                float m0 = fmaxf(fmaxf(fmaxf(s[0], s[1]), fmaxf(s[2], s[3])),
                                 fmaxf(fmaxf(s[4], s[5]), fmaxf(s[6], s[7])));
                float m1 = fmaxf(fmaxf(fmaxf(s[8], s[9]), fmaxf(s[10], s[11])),
                                 fmaxf(fmaxf(s[12], s[13]), fmaxf(s[14], s[15])));
                float mx = fmaxf(m0, m1);
                mx = fmaxf(mx, __shfl_xor(mx, 16));
                mx = fmaxf(mx, __shfl_xor(mx, 32));
#pragma unroll
                for (int k2 = 0; k2 < 16; ++k2) s[k2] = __expf(s[k2] - mx);
                // tree sum
                float s01 = (s[0] + s[1]) + (s[2] + s[3]);
                float s23 = (s[4] + s[5]) + (s[6] + s[7]);
                float s45 = (s[8] + s[9]) + (s[10] + s[11]);
                float s67 = (s[12] + s[13]) + (s[14] + s[15]);
                float sum = (s01 + s23) + (s45 + s67);
                sum += __shfl_xor(sum, 16);
                sum += __shfl_xor(sum, 32);
                float linv = 1.0f / sum;
                // store normalized P, XOR-chunk swizzle: row i, chunk tc^(i&7)
#pragma unroll
                for (int mt = 0; mt < 4; ++mt) {
                    int tc = 2 * mt + (g >> 1);
                    bf16x4 p4 = {(bf16_t)(s[mt * 4 + 0] * linv), (bf16_t)(s[mt * 4 + 1] * linv),
                                 (bf16_t)(s[mt * 4 + 2] * linv), (bf16_t)(s[mt * 4 + 3] * linv)};
                    *(bf16x4*)(Ph + i * 128 + ((tc ^ (i & 7)) << 4) + ((g & 1) << 3)) = p4;
                }
            }

            // O[i][d] = sum_t P[i][t] v[t][d];  A=P (swizzled), B=vT (vector!)
#pragma unroll
            for (int ks = 0; ks < 2; ++ks) {
                bf16x8 Bv[2];
#pragma unroll
                for (int nd = 0; nd < 2; ++nd)
                    Bv[nd] = ld_b8_2x(vh + (nd * 16 + c) * VTP + ks * 32 + g * 8);
#pragma unroll
                for (int nl = 0; nl < 2; ++nl) {
                    int i = (2 * u + nl) * 16 + c;
                    bf16x8 Ap = *(const bf16x8*)(Ph + i * 128 + (((4 * ks + g) ^ (i & 7)) << 4));
#pragma unroll
                    for (int nd = 0; nd < 2; ++nd)
                        oacc[nl][nd] = MFMA16(Ap, Bv[nd], oacc[nl][nd]);
                }
            }

            // attn_out -> aoS (alias of qS; safe after B2e)
#pragma unroll
            for (int nl = 0; nl < 2; ++nl)
#pragma unroll
                for (int nd = 0; nd < 2; ++nd) {
                    f32x4 o = oacc[nl][nd];
#pragma unroll
                    for (int r = 0; r < 4; ++r) {
                        int i = (2 * u + nl) * 16 + 4 * g + r;
                        aoS[i * AOP + h * 32 + nd * 16 + c] = (bf16_t)o[r];
                    }
                }
        }
        __syncthreads();  // B3: ao ready; region R (pS) free

        // write next window's x into R (overlaps Ao hoist below)
        if (it < 15) {
#pragma unroll
            for (int i2 = 0; i2 < 3; ++i2) {
                f32x4 v = xr[i2];
                bf16x4 o = {(bf16_t)v[0], (bf16_t)v[1], (bf16_t)v[2], (bf16_t)v[3]};
                *(bf16x4*)(xS + tokA[i2] * AOP + cA[i2] * 4) = o;
            }
        }

        // hoist all 6 Ao fragments so B4 can fire early and phase C's MFMA
        // tail overlaps the next window's phase A
        bf16x8 Ao[6];
#pragma unroll
        for (int ks = 0; ks < 6; ++ks)
            Ao[ks] = ld_b8_2x(aoS + (mtc * 16 + c) * AOP + ks * 32 + g * 8);
        __syncthreads();  // B4: aoS reads done + next-x written

        // =========== Phase C: out = attn_out @ w_proj + bias ===========
        f32x4 pacc[3];
#pragma unroll
        for (int j = 0; j < 3; ++j) pacc[j] = (f32x4){0.f, 0.f, 0.f, 0.f};

        bf16x8 Bwc[3];
#pragma unroll
        for (int j = 0; j < 3; ++j)
            Bwc[j] = *(const bf16x8*)(w2B + (((size_t)(g3 * 3 + j)) * 64 + lane) * 8);
#pragma unroll
        for (int ks = 0; ks < 6; ++ks) {
            bf16x8 Bwn[3];
            if (ks < 5) {
#pragma unroll
                for (int j = 0; j < 3; ++j)
                    Bwn[j] = *(const bf16x8*)(w2B + (((size_t)(ks + 1) * 12 + g3 * 3 + j) * 64 + lane) * 8);
            }
#pragma unroll
            for (int j = 0; j < 3; ++j)
                pacc[j] = MFMA16(Ao[ks], Bwc[j], pacc[j]);
            if (ks < 5) {
#pragma unroll
                for (int j = 0; j < 3; ++j) Bwc[j] = Bwn[j];
            }
        }

        float* ob = out + (size_t)(b + 256 * it) * 9408;
#pragma unroll
        for (int j = 0; j < 3; ++j) {
            int ch2 = (g3 * 3 + j) * 16 + c;
            f32x4 a2 = pacc[j];
#pragma unroll
            for (int r = 0; r < 4; ++r) {
                int tok = mtc * 16 + 4 * g + r;
                if (tok < 49) ob[(size_t)tok * 192 + ch2] = a2[r] + bbv[j];
            }
        }
    }
}

// ---------------------------------------------------------------------------
extern "C" void kernel_launch(void* const* d_in, const int* in_sizes, int n_in,
                              void* d_out, int out_size, void* d_ws, size_t ws_size,
                              hipStream_t stream) {
    const float* x     = (const float*)d_in[0];
    const float* mask  = (const float*)d_in[1];
    const float* wqkv  = (const float*)d_in[2];
    const float* wproj = (const float*)d_in[3];
    const float* bias  = (const float*)d_in[4];
    float* out = (float*)d_out;

    bf16_t* wA  = (bf16_t*)d_ws;   // 110592 bf16
    bf16_t* w2B = wA + 110592;     //  36864 bf16

    prep_weights<<<576, 256, 0, stream>>>(wqkv, wproj, wA, w2B);
    fused_window_attn<<<256, 1024, 0, stream>>>(x, mask, wA, w2B, bias, out);
}

// Round 2
// 408.679 us; speedup vs baseline: 2.1307x; 2.1307x over previous
//
#include <hip/hip_runtime.h>

using bf16_t = __bf16;
using bf16x4 = __bf16 __attribute__((ext_vector_type(4)));
using bf16x8 = __bf16 __attribute__((ext_vector_type(8)));
using f32x4  = float  __attribute__((ext_vector_type(4)));

#define MFMA16(a, b, c) __builtin_amdgcn_mfma_f32_16x16x32_bf16((a), (b), (c), 0, 0, 0)

// 8-byte-aligned bf16x8 load as two b64s
__device__ __forceinline__ bf16x8 ld_b8_2x(const bf16_t* p) {
    bf16x4 lo = *(const bf16x4*)p;
    bf16x4 hi = *(const bf16x4*)(p + 4);
    bf16x8 r;
    r[0] = lo[0]; r[1] = lo[1]; r[2] = lo[2]; r[3] = lo[3];
    r[4] = hi[0]; r[5] = hi[1]; r[6] = hi[2]; r[7] = hi[3];
    return r;
}

// ---------------------------------------------------------------------------
// Prep: swizzle weights into fragment order (bf16) in workspace. (unchanged)
//  wA  [mt(36)][ks(6)][lane(64)][8] : A-frag of w_qkv^T
//  w2B [ks(6)][nt(12)][lane(64)][8] : B-frag of w_proj
// ---------------------------------------------------------------------------
__global__ void prep_weights(const float* __restrict__ wqkv,
                             const float* __restrict__ wproj,
                             bf16_t* __restrict__ wA,
                             bf16_t* __restrict__ w2B) {
    int idx = blockIdx.x * 256 + threadIdx.x;
    const int N1 = 36 * 6 * 64 * 8;  // 110592
    if (idx < N1) {
        int j = idx & 7, L = (idx >> 3) & 63, q = idx >> 9;
        int ks = q % 6, mt = q / 6;
        int cc = ks * 32 + (L >> 4) * 8 + j;
        int ch = mt * 16 + (L & 15);
        wA[idx] = (bf16_t)wqkv[cc * 576 + ch];
    } else {
        int idx2 = idx - N1;
        if (idx2 < 6 * 12 * 64 * 8) {
            int j = idx2 & 7, L = (idx2 >> 3) & 63, q = idx2 >> 9;
            int nt = q % 12, ks = q / 12;
            int cc = ks * 32 + (L >> 4) * 8 + j;
            int ch = nt * 16 + (L & 15);
            w2B[idx2] = (bf16_t)wproj[cc * 192 + ch];
        }
    }
}

// ---------------------------------------------------------------------------
// Fused window attention: 4096 blocks x 1024 threads (16 waves), 1 window/blk
// (non-persistent: round-1's persistent variant spilled ~180 KB/window of
//  scratch — 1024-thread blocks cap VGPRs at 128, no cross-phase pipelining)
//
// LDS map (bytes), total 145920:
//   [0,      30720)  qS  [6][64][40]     (aliased after B2e by aoS [64][204])
//   [30720,  61440)  kS  [6][64][40]
//   [61440,  87552)  vT  [6][32][68]     V TRANSPOSED: [head][d][tok]
//   [87552,  96768)  pmS [64][72]
//   [96768, 145920)  xS  [64][204] (phase A input)
//                    aliased by pS [6][64][128B] XOR-chunk-swizzled (phase B)
// Barriers: B0 (x,pm ready), B1 (qkv ready), B2e (q/k frag reads done; cheap),
//   B3 (ao ready).
// ---------------------------------------------------------------------------
__global__ __launch_bounds__(1024, 4) void fused_window_attn(
    const float* __restrict__ x,     // [4096][49][192]
    const float* __restrict__ mask,  // [64][1][49][49]
    const bf16_t* __restrict__ wA,
    const bf16_t* __restrict__ w2B,
    const float* __restrict__ bias,  // [192]
    float* __restrict__ out)         // [4096][49][192]
{
    constexpr int QP  = 40;   // q/k pitch (elems)
    constexpr int VTP = 68;   // vT pitch (elems), d-major rows
    constexpr int PMP = 72;   // premask pitch
    constexpr int AOP = 204;  // attn_out / staged-x pitch

    __shared__ __align__(16) char smem[145920];
    bf16_t* qS  = (bf16_t*)smem;            // elem offsets
    bf16_t* kS  = qS + 15360;
    bf16_t* vT  = qS + 30720;               // [6][32][68]
    bf16_t* pmS = qS + 43776;
    char*   pB  = smem + 96768;             // swizzled P (byte-addressed)
    bf16_t* xS  = (bf16_t*)(smem + 96768);  // alias pB
    bf16_t* aoS = (bf16_t*)smem;            // alias qS

    const int b    = blockIdx.x;
    const int tid  = threadIdx.x;
    const int wid  = tid >> 6;   // 0..15
    const int lane = tid & 63;
    const int g    = lane >> 4;
    const int c    = lane & 15;

    // phase C wave tasks + bias hoist (3 L2 loads, overlap x staging)
    const int mtc = wid & 3;
    const int g3  = wid >> 2;
    float bbv[3];
#pragma unroll
    for (int j = 0; j < 3; ++j) bbv[j] = bias[(g3 * 3 + j) * 16 + c];

    // ---- stage x (fp32->bf16, zero-pad tok>=49) into xS [64][204] ----
    const float* xb = x + (size_t)b * (49 * 192);
    for (int ch4 = tid; ch4 < 64 * 48; ch4 += 1024) {
        int tok = ch4 / 48, c4 = ch4 % 48;
        f32x4 v = (f32x4){0.f, 0.f, 0.f, 0.f};
        if (tok < 49) v = *(const f32x4*)(xb + tok * 192 + c4 * 4);
        bf16x4 o = {(bf16_t)v[0], (bf16_t)v[1], (bf16_t)v[2], (bf16_t)v[3]};
        *(bf16x4*)(xS + tok * AOP + c4 * 4) = o;
    }
    // ---- stage premask [64][72] ----
    const float* mw = mask + (size_t)(b & 63) * (49 * 49);
    for (int idx = tid; idx < 64 * 64; idx += 1024) {
        int i = idx >> 6, t = idx & 63;
        float v;
        if (t < 49) v = (i < 49) ? mw[i * 49 + t] : 0.0f;
        else        v = -1e30f;
        pmS[i * PMP + t] = (bf16_t)v;
    }
    __syncthreads();  // B0: xS, pmS ready

    // =========== Phase A: qkv^T = w_qkv^T (A) * x^T (B) ===========
    const int nmt = (wid < 4) ? 3 : 2;
    const int mt0 = (wid < 4) ? wid * 3 : 12 + (wid - 4) * 2;

    f32x4 acc[3][4];
#pragma unroll
    for (int m = 0; m < 3; ++m)
#pragma unroll
        for (int n = 0; n < 4; ++n) acc[m][n] = (f32x4){0.f, 0.f, 0.f, 0.f};

#pragma unroll
    for (int ks = 0; ks < 6; ++ks) {
        bf16x8 Bf[4];
#pragma unroll
        for (int nt = 0; nt < 4; ++nt)
            Bf[nt] = ld_b8_2x(xS + (nt * 16 + c) * AOP + ks * 32 + g * 8);
#pragma unroll
        for (int m = 0; m < 3; ++m) {
            if (m < nmt) {
                int mt = mt0 + m;
                bf16x8 Af = *(const bf16x8*)(wA + (((size_t)mt * 6 + ks) * 64 + lane) * 8);
#pragma unroll
                for (int nt = 0; nt < 4; ++nt)
                    acc[m][nt] = MFMA16(Af, Bf[nt], acc[m][nt]);
            }
        }
    }

    // route: q,k -> [h][tok][40] row-major; v -> TRANSPOSED [h][d][68]
#pragma unroll
    for (int m = 0; m < 3; ++m) {
        if (m < nmt) {
            int mt  = mt0 + m;
            int typ = mt / 12;                       // wave-uniform
            int rel = (mt - typ * 12) * 16 + g * 4;  // 0..191 in q/k/v
            int hh  = rel >> 5;
            int dd0 = rel & 31;
#pragma unroll
            for (int nt = 0; nt < 4; ++nt) {
                int tok = nt * 16 + c;
                f32x4 a = acc[m][nt];
                if (typ == 2) {
#pragma unroll
                    for (int r = 0; r < 4; ++r)
                        vT[hh * (32 * VTP) + (dd0 + r) * VTP + tok] = (bf16_t)a[r];
                } else {
                    bf16x4 v4 = {(bf16_t)a[0], (bf16_t)a[1], (bf16_t)a[2], (bf16_t)a[3]};
                    if (typ == 0) *(bf16x4*)(qS + hh * (64 * QP) + tok * QP + dd0) = v4;
                    else          *(bf16x4*)(kS + hh * (64 * QP) + tok * QP + dd0) = v4;
                }
            }
        }
    }
    __syncthreads();  // B1: qkv + pm ready; xS dead (region becomes pS)

    // =========== Phase B: attention. 12 wave-tasks = head(6) x i-half(2) ====
    const int h = wid >> 1;
    const int u = wid & 1;

    bf16x8 Ak[4], Bq[2];
    if (wid < 12) {
        const bf16_t* qh = qS + h * (64 * QP);
        const bf16_t* kh = kS + h * (64 * QP);
#pragma unroll
        for (int mt = 0; mt < 4; ++mt)
            Ak[mt] = *(const bf16x8*)(kh + (mt * 16 + c) * QP + g * 8);
#pragma unroll
        for (int nl = 0; nl < 2; ++nl)
            Bq[nl] = *(const bf16x8*)(qh + ((2 * u + nl) * 16 + c) * QP + g * 8);
    }
    __syncthreads();  // B2e (cheap): all qS/kS reads done -> aoS writes legal

    if (wid < 12) {
        char*         Ph = pB + h * 8192;  // 64 rows x 128 B, swizzled
        const bf16_t* vh = vT + h * (32 * VTP);

        // S^T[t][i] = sum_d k[t][d] q[i][d]; A=k (4 mt), B=q (2 nt)
        f32x4 sacc[4][2];
#pragma unroll
        for (int mt = 0; mt < 4; ++mt)
#pragma unroll
            for (int nl = 0; nl < 2; ++nl) sacc[mt][nl] = (f32x4){0.f, 0.f, 0.f, 0.f};
#pragma unroll
        for (int mt = 0; mt < 4; ++mt)
#pragma unroll
            for (int nl = 0; nl < 2; ++nl)
                sacc[mt][nl] = MFMA16(Ak[mt], Bq[nl], sacc[mt][nl]);

        // softmax over t for i-rows of this half; fold 1/l into P
        const float scale = 0.17677669529663687f;  // 32^-0.5
#pragma unroll
        for (int nl = 0; nl < 2; ++nl) {
            int i = (2 * u + nl) * 16 + c;
            float s[16];
#pragma unroll
            for (int mt = 0; mt < 4; ++mt) {
                bf16x4 pmv = *(const bf16x4*)(pmS + i * PMP + mt * 16 + g * 4);
#pragma unroll
                for (int r = 0; r < 4; ++r)
                    s[mt * 4 + r] = sacc[mt][nl][r] * scale + (float)pmv[r];
            }
            // tree max (v_max3-friendly groupings)
            float mx = fmaxf(
                fmaxf(fmaxf(fmaxf(s[0], s[1]), s[2]), fmaxf(fmaxf(s[3], s[4]), s[5])),
                fmaxf(fmaxf(fmaxf(s[6], s[7]), s[8]), fmaxf(fmaxf(s[9], s[10]), s[11])));
            mx = fmaxf(mx, fmaxf(fmaxf(s[12], s[13]), fmaxf(s[14], s[15])));
            mx = fmaxf(mx, __shfl_xor(mx, 16));
            mx = fmaxf(mx, __shfl_xor(mx, 32));
#pragma unroll
            for (int k2 = 0; k2 < 16; ++k2) s[k2] = __expf(s[k2] - mx);
            // tree sum
            float s01 = (s[0] + s[1]) + (s[2] + s[3]);
            float s23 = (s[4] + s[5]) + (s[6] + s[7]);
            float s45 = (s[8] + s[9]) + (s[10] + s[11]);
            float s67 = (s[12] + s[13]) + (s[14] + s[15]);
            float sum = (s01 + s23) + (s45 + s67);
            sum += __shfl_xor(sum, 16);
            sum += __shfl_xor(sum, 32);
            float linv = 1.0f / sum;
            // store normalized P, XOR-chunk swizzle: row i, chunk tc^(i&7)
#pragma unroll
            for (int mt = 0; mt < 4; ++mt) {
                int tc = 2 * mt + (g >> 1);
                bf16x4 p4 = {(bf16_t)(s[mt * 4 + 0] * linv), (bf16_t)(s[mt * 4 + 1] * linv),
                             (bf16_t)(s[mt * 4 + 2] * linv), (bf16_t)(s[mt * 4 + 3] * linv)};
                *(bf16x4*)(Ph + i * 128 + ((tc ^ (i & 7)) << 4) + ((g & 1) << 3)) = p4;
            }
        }

        // O[i][d] = sum_t P[i][t] v[t][d];  A=P (swizzled b128), B=vT (vector)
        f32x4 oacc[2][2];
#pragma unroll
        for (int a0 = 0; a0 < 2; ++a0)
#pragma unroll
            for (int a1 = 0; a1 < 2; ++a1) oacc[a0][a1] = (f32x4){0.f, 0.f, 0.f, 0.f};

#pragma unroll
        for (int ks = 0; ks < 2; ++ks) {
            bf16x8 Bv[2];
#pragma unroll
            for (int nd = 0; nd < 2; ++nd)
                Bv[nd] = ld_b8_2x(vh + (nd * 16 + c) * VTP + ks * 32 + g * 8);
#pragma unroll
            for (int nl = 0; nl < 2; ++nl) {
                int i = (2 * u + nl) * 16 + c;
                bf16x8 Ap = *(const bf16x8*)(Ph + i * 128 + (((4 * ks + g) ^ (i & 7)) << 4));
#pragma unroll
                for (int nd = 0; nd < 2; ++nd)
                    oacc[nl][nd] = MFMA16(Ap, Bv[nd], oacc[nl][nd]);
            }
        }

        // attn_out -> aoS (alias of qS; legal after B2e)
#pragma unroll
        for (int nl = 0; nl < 2; ++nl)
#pragma unroll
            for (int nd = 0; nd < 2; ++nd) {
                f32x4 o = oacc[nl][nd];
#pragma unroll
                for (int r = 0; r < 4; ++r) {
                    int i = (2 * u + nl) * 16 + 4 * g + r;
                    aoS[i * AOP + h * 32 + nd * 16 + c] = (bf16_t)o[r];
                }
            }
    }
    __syncthreads();  // B3: attn_out ready

    // =========== Phase C: out = attn_out @ w_proj + bias ===========
    f32x4 pacc[3];
#pragma unroll
    for (int j = 0; j < 3; ++j) pacc[j] = (f32x4){0.f, 0.f, 0.f, 0.f};

#pragma unroll
    for (int ks = 0; ks < 6; ++ks) {
        bf16x8 Ao = ld_b8_2x(aoS + (mtc * 16 + c) * AOP + ks * 32 + g * 8);
#pragma unroll
        for (int j = 0; j < 3; ++j) {
            bf16x8 Bw = *(const bf16x8*)(w2B + (((size_t)ks * 12 + g3 * 3 + j) * 64 + lane) * 8);
            pacc[j] = MFMA16(Ao, Bw, pacc[j]);
        }
    }

    float* ob = out + (size_t)b * (49 * 192);
#pragma unroll
    for (int j = 0; j < 3; ++j) {
        int ch2 = (g3 * 3 + j) * 16 + c;
        f32x4 a = pacc[j];
#pragma unroll
        for (int r = 0; r < 4; ++r) {
            int tok = mtc * 16 + 4 * g + r;
            if (tok < 49) ob[(size_t)tok * 192 + ch2] = a[r] + bbv[j];
        }
    }
}

// ---------------------------------------------------------------------------
extern "C" void kernel_launch(void* const* d_in, const int* in_sizes, int n_in,
                              void* d_out, int out_size, void* d_ws, size_t ws_size,
                              hipStream_t stream) {
    const float* x     = (const float*)d_in[0];
    const float* mask  = (const float*)d_in[1];
    const float* wqkv  = (const float*)d_in[2];
    const float* wproj = (const float*)d_in[3];
    const float* bias  = (const float*)d_in[4];
    float* out = (float*)d_out;

    bf16_t* wA  = (bf16_t*)d_ws;   // 110592 bf16
    bf16_t* w2B = wA + 110592;     //  36864 bf16

    prep_weights<<<576, 256, 0, stream>>>(wqkv, wproj, wA, w2B);
    fused_window_attn<<<4096, 1024, 0, stream>>>(x, mask, wA, w2B, bias, out);
}

// Round 3
// 376.228 us; speedup vs baseline: 2.3144x; 1.0863x over previous
//
#include <hip/hip_runtime.h>

using bf16_t = __bf16;
using bf16x4 = __bf16 __attribute__((ext_vector_type(4)));
using bf16x8 = __bf16 __attribute__((ext_vector_type(8)));
using f32x4  = float  __attribute__((ext_vector_type(4)));

#define MFMA16(a, b, c) __builtin_amdgcn_mfma_f32_16x16x32_bf16((a), (b), (c), 0, 0, 0)

// 8-byte-aligned bf16x8 load as two b64s
__device__ __forceinline__ bf16x8 ld_b8_2x(const bf16_t* p) {
    bf16x4 lo = *(const bf16x4*)p;
    bf16x4 hi = *(const bf16x4*)(p + 4);
    bf16x8 r;
    r[0] = lo[0]; r[1] = lo[1]; r[2] = lo[2]; r[3] = lo[3];
    r[4] = hi[0]; r[5] = hi[1]; r[6] = hi[2]; r[7] = hi[3];
    return r;
}

// ---------------------------------------------------------------------------
// Prep: swizzle weights into fragment order (bf16) in workspace. (unchanged)
//  wA  [mt(36)][ks(6)][lane(64)][8] : A-frag of w_qkv^T
//  w2B [ks(6)][nt(12)][lane(64)][8] : B-frag of w_proj
// ---------------------------------------------------------------------------
__global__ void prep_weights(const float* __restrict__ wqkv,
                             const float* __restrict__ wproj,
                             bf16_t* __restrict__ wA,
                             bf16_t* __restrict__ w2B) {
    int idx = blockIdx.x * 256 + threadIdx.x;
    const int N1 = 36 * 6 * 64 * 8;  // 110592
    if (idx < N1) {
        int j = idx & 7, L = (idx >> 3) & 63, q = idx >> 9;
        int ks = q % 6, mt = q / 6;
        int cc = ks * 32 + (L >> 4) * 8 + j;
        int ch = mt * 16 + (L & 15);
        wA[idx] = (bf16_t)wqkv[cc * 576 + ch];
    } else {
        int idx2 = idx - N1;
        if (idx2 < 6 * 12 * 64 * 8) {
            int j = idx2 & 7, L = (idx2 >> 3) & 63, q = idx2 >> 9;
            int nt = q % 12, ks = q / 12;
            int cc = ks * 32 + (L >> 4) * 8 + j;
            int ch = nt * 16 + (L & 15);
            w2B[idx2] = (bf16_t)wproj[cc * 192 + ch];
        }
    }
}

// ---------------------------------------------------------------------------
// Fused window attention: 4096 blocks x 512 threads (8 waves), 1 window/blk,
// sized for 2 blocks/CU (LDS 81408 <= 81920; reg budget 128 incl AGPR).
//
// LDS map (bytes), total 81408:
//   [0,     27648)  qS  [6][64][36]
//   [27648, 55296)  kS  [6][64][36]   (aliased after B1b by aoS [64][204])
//   [55296, 81408)  xS  [64][204]     (phase A input)
//                   aliased after B1 by vT [6][32][68] (V transposed [h][d][t])
// P never touches LDS: PV A-frags built from softmax registers via 4-lane-
// group shuffles (lane (g,c) pulls quads from lanes 32*(g&1)+c and +16,
// tile mt' = 2ks + (g>>1)).
// premask read from global (L1-resident) with register predication.
// Barriers: B0 (xS ready), B1 (q/k in LDS; xS dead), B1b (vT written, Ak
// loaded -> kS reusable as aoS), B3 (ao ready).
// ---------------------------------------------------------------------------
__global__ __launch_bounds__(512, 4) void fused_window_attn(
    const float* __restrict__ x,     // [4096][49][192]
    const float* __restrict__ mask,  // [64][1][49][49]
    const bf16_t* __restrict__ wA,
    const bf16_t* __restrict__ w2B,
    const float* __restrict__ bias,  // [192]
    float* __restrict__ out)         // [4096][49][192]
{
    constexpr int QP  = 36;   // q/k pitch (elems)
    constexpr int VTP = 68;   // vT pitch (elems), d-major rows
    constexpr int AOP = 204;  // attn_out / staged-x pitch

    __shared__ __align__(16) char smem[81408];
    bf16_t* qS  = (bf16_t*)smem;       // elem offsets
    bf16_t* kS  = qS + 13824;          // 6*64*36
    bf16_t* xS  = kS + 13824;          // [64][204] = 13056 elems
    bf16_t* vT  = xS;                  // alias: [6][32][68] = 13056 elems
    bf16_t* aoS = kS;                  // alias: [64][204] = 13056 <= 13824

    const int b    = blockIdx.x;
    const int tid  = threadIdx.x;
    const int wid  = tid >> 6;   // 0..7
    const int lane = tid & 63;
    const int g    = lane >> 4;
    const int c    = lane & 15;

    // phase C wave tasks + bias hoist
    const int mtc = wid & 3;
    const int g3  = wid >> 1 >> 1;  // wid>>2: 0..1
    float bbv[6];
#pragma unroll
    for (int j = 0; j < 6; ++j) bbv[j] = bias[(g3 * 6 + j) * 16 + c];

    // ---- stage x (fp32->bf16, zero-pad tok>=49) into xS [64][204] ----
    const float* xb = x + (size_t)b * (49 * 192);
    for (int ch4 = tid; ch4 < 64 * 48; ch4 += 512) {
        int tok = ch4 / 48, c4 = ch4 % 48;
        f32x4 v = (f32x4){0.f, 0.f, 0.f, 0.f};
        if (tok < 49) v = *(const f32x4*)(xb + tok * 192 + c4 * 4);
        bf16x4 o = {(bf16_t)v[0], (bf16_t)v[1], (bf16_t)v[2], (bf16_t)v[3]};
        *(bf16x4*)(xS + tok * AOP + c4 * 4) = o;
    }
    __syncthreads();  // B0: xS ready

    // =========== Phase A: qkv^T = w_qkv^T (A) * x^T (B) ===========
    // wave w owns mts {w, w+8, w+16, w+24} (+{w+32} if w<4); w+24/w+32 are
    // always V (held in regs), the rest always q/k (stored immediately).
    const f32x4 ZV = (f32x4){0.f, 0.f, 0.f, 0.f};
    f32x4 aA[4], aB[4], vacc0[4], vacc1[4];

#define PASS2(MTA, MTB, ACCA, ACCB)                                            \
    {                                                                          \
        _Pragma("unroll") for (int n = 0; n < 4; ++n) {                        \
            ACCA[n] = ZV; ACCB[n] = ZV;                                        \
        }                                                                      \
        _Pragma("unroll") for (int ks = 0; ks < 6; ++ks) {                     \
            bf16x8 Bf[4];                                                      \
            _Pragma("unroll") for (int nt = 0; nt < 4; ++nt)                   \
                Bf[nt] = ld_b8_2x(xS + (nt * 16 + c) * AOP + ks * 32 + g * 8); \
            bf16x8 AfA = *(const bf16x8*)(wA + (((size_t)(MTA) * 6 + ks) * 64 + lane) * 8); \
            bf16x8 AfB = *(const bf16x8*)(wA + (((size_t)(MTB) * 6 + ks) * 64 + lane) * 8); \
            _Pragma("unroll") for (int nt = 0; nt < 4; ++nt) {                 \
                ACCA[nt] = MFMA16(AfA, Bf[nt], ACCA[nt]);                      \
                ACCB[nt] = MFMA16(AfB, Bf[nt], ACCB[nt]);                      \
            }                                                                  \
        }                                                                      \
    }

    // route q/k acc -> LDS row-major [h][tok][36]
    auto routeQK = [&](int mt, f32x4 (&acc)[4]) {
        int typ = mt / 12;                       // 0=q, 1=k (wave-uniform)
        int rel = (mt - typ * 12) * 16 + g * 4;  // 0..191
        int hh  = rel >> 5;
        int dd0 = rel & 31;
        bf16_t* base = typ ? kS : qS;
#pragma unroll
        for (int nt = 0; nt < 4; ++nt) {
            int tok = nt * 16 + c;
            bf16x4 v4 = {(bf16_t)acc[nt][0], (bf16_t)acc[nt][1],
                         (bf16_t)acc[nt][2], (bf16_t)acc[nt][3]};
            *(bf16x4*)(base + hh * (64 * QP) + tok * QP + dd0) = v4;
        }
    };

    PASS2(wid, wid + 8, aA, aB);            // both q/k
    routeQK(wid, aA);
    routeQK(wid + 8, aB);
    PASS2(wid + 16, wid + 24, aA, vacc0);   // k + v(held)
    routeQK(wid + 16, aA);
    if (wid < 4) {                           // solo v pass -> vacc1
#pragma unroll
        for (int n = 0; n < 4; ++n) vacc1[n] = ZV;
#pragma unroll
        for (int ks = 0; ks < 6; ++ks) {
            bf16x8 Bf[4];
#pragma unroll
            for (int nt = 0; nt < 4; ++nt)
                Bf[nt] = ld_b8_2x(xS + (nt * 16 + c) * AOP + ks * 32 + g * 8);
            bf16x8 Af = *(const bf16x8*)(wA + (((size_t)(wid + 32) * 6 + ks) * 64 + lane) * 8);
#pragma unroll
            for (int nt = 0; nt < 4; ++nt) vacc1[nt] = MFMA16(Af, Bf[nt], vacc1[nt]);
        }
    }
    __syncthreads();  // B1: q/k in LDS; xS dead (region becomes vT)

    // ---- write held V transposed into vT [h][d][68] ----
    auto routeV = [&](int mt, f32x4 (&acc)[4]) {
        int rel = (mt - 24) * 16 + g * 4;
        int hh  = rel >> 5;
        int dd0 = rel & 31;
#pragma unroll
        for (int nt = 0; nt < 4; ++nt)
#pragma unroll
            for (int r = 0; r < 4; ++r)
                vT[hh * (32 * VTP) + (dd0 + r) * VTP + nt * 16 + c] = (bf16_t)acc[nt][r];
    };
    routeV(wid + 24, vacc0);
    if (wid < 4) routeV(wid + 32, vacc1);

    // phase-B K frags (all kS reads happen before B1b -> kS reusable as aoS)
    const int h = wid;  // head for waves 0..5
    bf16x8 Ak[4];
    if (wid < 6) {
        const bf16_t* kh = kS + h * (64 * QP);
#pragma unroll
        for (int mt = 0; mt < 4; ++mt)
            Ak[mt] = ld_b8_2x(kh + (mt * 16 + c) * QP + g * 8);
    }
    __syncthreads();  // B1b: vT ready; kS reads done

    // =========== Phase B: wave h handles head h; u-halves sequential =======
    if (wid < 6) {
        const bf16_t* qh = qS + h * (64 * QP);
        const bf16_t* vh = vT + h * (32 * VTP);
        const float*  mw = mask + (size_t)(b & 63) * (49 * 49);
        const float   scale = 0.17677669529663687f;  // 32^-0.5
        const int  L1s = ((lane >> 4) & 1) * 32 + c;
        const int  L2s = L1s + 16;
        const bool hisel = (g >= 2);

#pragma unroll
        for (int u = 0; u < 2; ++u) {
            // S^T[t][i] = sum_d k[t][d] q[i][d]; A=k (4 mt), B=q (2 nl)
            bf16x8 Bq[2];
#pragma unroll
            for (int nl = 0; nl < 2; ++nl)
                Bq[nl] = ld_b8_2x(qh + ((u * 2 + nl) * 16 + c) * QP + g * 8);
            f32x4 sacc[4][2];
#pragma unroll
            for (int mt = 0; mt < 4; ++mt)
#pragma unroll
                for (int nl = 0; nl < 2; ++nl) sacc[mt][nl] = ZV;
#pragma unroll
            for (int mt = 0; mt < 4; ++mt)
#pragma unroll
                for (int nl = 0; nl < 2; ++nl)
                    sacc[mt][nl] = MFMA16(Ak[mt], Bq[nl], sacc[mt][nl]);

            // softmax over t (in-thread 16 + shfl over g-groups); premask from
            // global with register predication; pack P*linv -> dwords D
            unsigned int D[2][4][2];
#pragma unroll
            for (int nl = 0; nl < 2; ++nl) {
                int i = u * 32 + nl * 16 + c;
                float s[16];
#pragma unroll
                for (int mt = 0; mt < 4; ++mt) {
                    int t0 = mt * 16 + g * 4;
                    float pmv[4];
                    if (i < 49) {
                        if (mt < 3) {
                            const float* mp = mw + i * 49 + t0;
                            pmv[0] = mp[0]; pmv[1] = mp[1];
                            pmv[2] = mp[2]; pmv[3] = mp[3];
                        } else {
#pragma unroll
                            for (int r = 0; r < 4; ++r)
                                pmv[r] = (t0 + r < 49) ? mw[i * 49 + t0 + r] : -1e30f;
                        }
                    } else {
#pragma unroll
                        for (int r = 0; r < 4; ++r)
                            pmv[r] = (t0 + r < 49) ? 0.0f : -1e30f;
                    }
#pragma unroll
                    for (int r = 0; r < 4; ++r)
                        s[mt * 4 + r] = sacc[mt][nl][r] * scale + pmv[r];
                }
                // tree max
                float m0 = fmaxf(fmaxf(fmaxf(s[0], s[1]), fmaxf(s[2], s[3])),
                                 fmaxf(fmaxf(s[4], s[5]), fmaxf(s[6], s[7])));
                float m1 = fmaxf(fmaxf(fmaxf(s[8], s[9]), fmaxf(s[10], s[11])),
                                 fmaxf(fmaxf(s[12], s[13]), fmaxf(s[14], s[15])));
                float mx = fmaxf(m0, m1);
                mx = fmaxf(mx, __shfl_xor(mx, 16));
                mx = fmaxf(mx, __shfl_xor(mx, 32));
#pragma unroll
                for (int k2 = 0; k2 < 16; ++k2) s[k2] = __expf(s[k2] - mx);
                float s01 = (s[0] + s[1]) + (s[2] + s[3]);
                float s23 = (s[4] + s[5]) + (s[6] + s[7]);
                float s45 = (s[8] + s[9]) + (s[10] + s[11]);
                float s67 = (s[12] + s[13]) + (s[14] + s[15]);
                float sum = (s01 + s23) + (s45 + s67);
                sum += __shfl_xor(sum, 16);
                sum += __shfl_xor(sum, 32);
                float linv = 1.0f / sum;
#pragma unroll
                for (int mt = 0; mt < 4; ++mt)
#pragma unroll
                    for (int h2 = 0; h2 < 2; ++h2) {
                        union { __bf16 hh2[2]; unsigned int uu; } bp;
                        bp.hh2[0] = (bf16_t)(s[mt * 4 + 2 * h2] * linv);
                        bp.hh2[1] = (bf16_t)(s[mt * 4 + 2 * h2 + 1] * linv);
                        D[nl][mt][h2] = bp.uu;
                    }
            }

            // O[i][d] = sum_t P[i][t] v[t][d]; A=P from shuffles, B=vT vector
            f32x4 oacc[2][2];
#pragma unroll
            for (int a0 = 0; a0 < 2; ++a0)
#pragma unroll
                for (int a1 = 0; a1 < 2; ++a1) oacc[a0][a1] = ZV;
#pragma unroll
            for (int ks = 0; ks < 2; ++ks) {
                bf16x8 Bv[2];
#pragma unroll
                for (int nd = 0; nd < 2; ++nd)
                    Bv[nd] = ld_b8_2x(vh + (nd * 16 + c) * VTP + ks * 32 + g * 8);
#pragma unroll
                for (int nl = 0; nl < 2; ++nl) {
                    unsigned int a0 = (unsigned)__shfl((int)D[nl][2 * ks][0], L1s);
                    unsigned int b0 = (unsigned)__shfl((int)D[nl][2 * ks + 1][0], L1s);
                    unsigned int a1 = (unsigned)__shfl((int)D[nl][2 * ks][1], L1s);
                    unsigned int b1 = (unsigned)__shfl((int)D[nl][2 * ks + 1][1], L1s);
                    unsigned int a2 = (unsigned)__shfl((int)D[nl][2 * ks][0], L2s);
                    unsigned int b2 = (unsigned)__shfl((int)D[nl][2 * ks + 1][0], L2s);
                    unsigned int a3 = (unsigned)__shfl((int)D[nl][2 * ks][1], L2s);
                    unsigned int b3 = (unsigned)__shfl((int)D[nl][2 * ks + 1][1], L2s);
                    union { unsigned int uu[4]; bf16x8 v; } ap;
                    ap.uu[0] = hisel ? b0 : a0;
                    ap.uu[1] = hisel ? b1 : a1;
                    ap.uu[2] = hisel ? b2 : a2;
                    ap.uu[3] = hisel ? b3 : a3;
#pragma unroll
                    for (int nd = 0; nd < 2; ++nd)
                        oacc[nl][nd] = MFMA16(ap.v, Bv[nd], oacc[nl][nd]);
                }
            }

            // attn_out -> aoS (alias of kS; legal after B1b)
#pragma unroll
            for (int nl = 0; nl < 2; ++nl)
#pragma unroll
                for (int nd = 0; nd < 2; ++nd) {
                    f32x4 o = oacc[nl][nd];
#pragma unroll
                    for (int r = 0; r < 4; ++r) {
                        int i = u * 32 + nl * 16 + 4 * g + r;
                        aoS[i * AOP + h * 32 + nd * 16 + c] = (bf16_t)o[r];
                    }
                }
        }
    }
    __syncthreads();  // B3: attn_out ready

    // =========== Phase C: out = attn_out @ w_proj + bias ===========
    // 48 tiles = mt(4) x ntile(12); wave -> (mtc, 6 ntiles at g3*6)
    f32x4 pacc[6];
#pragma unroll
    for (int j = 0; j < 6; ++j) pacc[j] = ZV;

#pragma unroll
    for (int ks = 0; ks < 6; ++ks) {
        bf16x8 Ao = ld_b8_2x(aoS + (mtc * 16 + c) * AOP + ks * 32 + g * 8);
#pragma unroll
        for (int j = 0; j < 6; ++j) {
            bf16x8 Bw = *(const bf16x8*)(w2B + (((size_t)ks * 12 + g3 * 6 + j) * 64 + lane) * 8);
            pacc[j] = MFMA16(Ao, Bw, pacc[j]);
        }
    }

    float* ob = out + (size_t)b * (49 * 192);
#pragma unroll
    for (int j = 0; j < 6; ++j) {
        int ch2 = (g3 * 6 + j) * 16 + c;
        f32x4 a = pacc[j];
#pragma unroll
        for (int r = 0; r < 4; ++r) {
            int tok = mtc * 16 + 4 * g + r;
            if (tok < 49) ob[(size_t)tok * 192 + ch2] = a[r] + bbv[j];
        }
    }
#undef PASS2
}

// ---------------------------------------------------------------------------
extern "C" void kernel_launch(void* const* d_in, const int* in_sizes, int n_in,
                              void* d_out, int out_size, void* d_ws, size_t ws_size,
                              hipStream_t stream) {
    const float* x     = (const float*)d_in[0];
    const float* mask  = (const float*)d_in[1];
    const float* wqkv  = (const float*)d_in[2];
    const float* wproj = (const float*)d_in[3];
    const float* bias  = (const float*)d_in[4];
    float* out = (float*)d_out;

    bf16_t* wA  = (bf16_t*)d_ws;   // 110592 bf16
    bf16_t* w2B = wA + 110592;     //  36864 bf16

    prep_weights<<<576, 256, 0, stream>>>(wqkv, wproj, wA, w2B);
    fused_window_attn<<<4096, 512, 0, stream>>>(x, mask, wA, w2B, bias, out);
}